// Round 1
// baseline (85.777 us; speedup 1.0000x reference)
//
#include <hip/hip_runtime.h>

#define BSZ 512
#define DIM 512
#define EPSF 1e-5f

// ---------------- Kernel A: row norms sq[i] = sum_k E[i,k]^2 ----------------
__global__ __launch_bounds__(64) void norms_kernel(const float* __restrict__ E,
                                                   float* __restrict__ sq) {
    const int row = blockIdx.x;
    const int lane = threadIdx.x;           // 64 lanes, one wave
    const float4* rp = (const float4*)(E + (size_t)row * DIM);
    float4 a = rp[lane];
    float4 b = rp[lane + 64];
    float s = a.x*a.x + a.y*a.y + a.z*a.z + a.w*a.w
            + b.x*b.x + b.y*b.y + b.z*b.z + b.w*b.w;
#pragma unroll
    for (int off = 32; off > 0; off >>= 1) s += __shfl_down(s, off);
    if (lane == 0) sq[row] = s;
}

// ------------- Kernel B: tiled E*E^T GEMM + distance transform --------------
__device__ __forceinline__ float dist_xform(float sa, float sb, float dot) {
    float v = sa - 2.0f * dot + sb;
    v = fmaxf(v, 0.0f);
    float z = (v == 0.0f) ? 1.0f : 0.0f;   // zmask per reference
    v = sqrtf(v + z * EPSF) + EPSF;
    return v * (1.0f - z);
}

__global__ __launch_bounds__(256) void dist_kernel(const float* __restrict__ E,
                                                   const float* __restrict__ sq,
                                                   float* __restrict__ d) {
    __shared__ float As[32][33];   // +1 pad: break bank conflicts on column reads
    __shared__ float Bs[32][33];
    const int bi = blockIdx.y * 32;
    const int bj = blockIdx.x * 32;
    const int tid = threadIdx.x;        // 256 threads
    const int tx = tid & 15;            // 16x16 thread tile, 2x2 outputs each
    const int ty = tid >> 4;
    const int lr = tid >> 3;            // staging: row 0..31
    const int lc = (tid & 7) * 4;       // staging: col 0,4,..,28 (float4)

    float acc00 = 0.f, acc01 = 0.f, acc10 = 0.f, acc11 = 0.f;

    for (int k0 = 0; k0 < DIM; k0 += 32) {
        float4 av = *(const float4*)(E + (size_t)(bi + lr) * DIM + k0 + lc);
        float4 bv = *(const float4*)(E + (size_t)(bj + lr) * DIM + k0 + lc);
        As[lr][lc]   = av.x; As[lr][lc+1] = av.y; As[lr][lc+2] = av.z; As[lr][lc+3] = av.w;
        Bs[lr][lc]   = bv.x; Bs[lr][lc+1] = bv.y; Bs[lr][lc+2] = bv.z; Bs[lr][lc+3] = bv.w;
        __syncthreads();
#pragma unroll
        for (int kk = 0; kk < 32; ++kk) {
            float a0 = As[ty*2][kk],   a1 = As[ty*2+1][kk];
            float b0 = Bs[tx*2][kk],   b1 = Bs[tx*2+1][kk];
            acc00 += a0 * b0; acc01 += a0 * b1;
            acc10 += a1 * b0; acc11 += a1 * b1;
        }
        __syncthreads();
    }

    const int i0 = bi + ty * 2;
    const int j0 = bj + tx * 2;
    const float sqi0 = sq[i0], sqi1 = sq[i0+1];
    const float sqj0 = sq[j0], sqj1 = sq[j0+1];
    d[(size_t)i0*BSZ + j0]         = dist_xform(sqi0, sqj0, acc00);
    d[(size_t)i0*BSZ + j0+1]       = dist_xform(sqi0, sqj1, acc01);
    d[(size_t)(i0+1)*BSZ + j0]     = dist_xform(sqi1, sqj0, acc10);
    d[(size_t)(i0+1)*BSZ + j0+1]   = dist_xform(sqi1, sqj1, acc11);
}

// ------------- Kernel C: per-anchor triplet sums (one block per anchor) -----
__global__ __launch_bounds__(256) void triplet_kernel(const float* __restrict__ d,
                                                      const int* __restrict__ labels,
                                                      float* __restrict__ partial) {
    const int a = blockIdx.x;
    const int tid = threadIdx.x;    // 256 threads
    __shared__ float drow[BSZ];
    __shared__ int   lab[BSZ];
    __shared__ int   poslist[BSZ];
    __shared__ int   npos_s;

    if (tid == 0) npos_s = 0;
    for (int t = tid; t < BSZ; t += 256) {
        lab[t]  = labels[t];
        drow[t] = d[(size_t)a * BSZ + t];
    }
    __syncthreads();

    const int la = lab[a];
    for (int t = tid; t < BSZ; t += 256) {
        if (lab[t] == la && t != a) {
            int idx = atomicAdd(&npos_s, 1);
            poslist[idx] = t;
        }
    }
    __syncthreads();

    const int npos = npos_s;
    const int nneg = BSZ - 1 - npos;   // everything not same-label (a itself excluded)
    float sum = 0.0f;
    int   cnt = 0;
    const int total = npos * BSZ;
    for (int idx = tid; idx < total; idx += 256) {
        const int p = poslist[idx >> 9];   // idx / 512
        const int n = idx & (BSZ - 1);     // idx % 512
        if (lab[n] != la) {
            const float v = drow[p] - drow[n];     // margin = 0
            if (v > 0.0f)  sum += v;               // sum of max(tl, 0)
            if (v > 1e-5f) cnt++;                  // num_positive
        }
    }

    // block reduce: wave shuffle then cross-wave via LDS
#pragma unroll
    for (int off = 32; off > 0; off >>= 1) {
        sum += __shfl_down(sum, off);
        cnt += __shfl_down(cnt, off);
    }
    __shared__ float wsum[4];
    __shared__ int   wcnt[4];
    const int wave = tid >> 6, lane = tid & 63;
    if (lane == 0) { wsum[wave] = sum; wcnt[wave] = cnt; }
    __syncthreads();
    if (tid == 0) {
        float S = wsum[0] + wsum[1] + wsum[2] + wsum[3];
        int   C = wcnt[0] + wcnt[1] + wcnt[2] + wcnt[3];
        partial[a]            = S;                         // sum of tl
        partial[BSZ + a]      = (float)C;                  // num_positive
        partial[2*BSZ + a]    = (float)npos * (float)nneg; // num_valid
    }
}

// ------------- Kernel D: final reduce + scalar epilogue ---------------------
__global__ __launch_bounds__(256) void final_kernel(const float* __restrict__ partial,
                                                    float* __restrict__ out) {
    const int tid = threadIdx.x;
    float s = partial[tid]         + partial[tid + 256];
    float c = partial[BSZ + tid]   + partial[BSZ + tid + 256];
    float v = partial[2*BSZ + tid] + partial[2*BSZ + tid + 256];
#pragma unroll
    for (int off = 32; off > 0; off >>= 1) {
        s += __shfl_down(s, off);
        c += __shfl_down(c, off);
        v += __shfl_down(v, off);
    }
    __shared__ float ws[4], wc[4], wv[4];
    const int wave = tid >> 6, lane = tid & 63;
    if (lane == 0) { ws[wave] = s; wc[wave] = c; wv[wave] = v; }
    __syncthreads();
    if (tid == 0) {
        float S = ws[0] + ws[1] + ws[2] + ws[3];
        float C = wc[0] + wc[1] + wc[2] + wc[3];
        float V = wv[0] + wv[1] + wv[2] + wv[3];
        out[0] = S / (C + 1e-5f);   // loss
        out[1] = C / (V + 1e-5f);   // fraction_positive
    }
}

extern "C" void kernel_launch(void* const* d_in, const int* in_sizes, int n_in,
                              void* d_out, int out_size, void* d_ws, size_t ws_size,
                              hipStream_t stream) {
    const float* E      = (const float*)d_in[0];   // embeddings [512,512] fp32
    const int*   labels = (const int*)d_in[1];     // labels [512] int
    float* out = (float*)d_out;                    // (loss, fraction_positive)

    float* sq      = (float*)d_ws;                 // 512 floats
    float* d       = sq + BSZ;                     // 512*512 floats (1 MB)
    float* partial = d + (size_t)BSZ * BSZ;        // 3*512 floats

    norms_kernel<<<BSZ, 64, 0, stream>>>(E, sq);
    dist_kernel<<<dim3(16, 16), 256, 0, stream>>>(E, sq, d);
    triplet_kernel<<<BSZ, 256, 0, stream>>>(d, labels, partial);
    final_kernel<<<1, 256, 0, stream>>>(partial, out);
}